// Round 1
// baseline (114855.383 us; speedup 1.0000x reference)
//
#include <hip/hip_runtime.h>
#include <math.h>

// RHN: SEQ=512, BATCH=64, HIDDEN=1024, 2 layers x 4 depth.
// Strategy round 0: fp16 MFMA (16x16x32), persistent-ish kernel with 64 WGs,
// one device barrier per depth micro-step (4096 total), W pre-transposed to
// [n][k] fp16 so A/B fragments are direct 16B global loads.

#define SEQ 512
#define NB 64
#define HID 1024
#define NH2 2048
#define NL 2
#define ND 4
#define NWG 64
#define SBUF (NB * HID)                       // 65536 elems per (phase,layer) state
#define WSLOT ((size_t)NH2 * (size_t)HID)     // 2097152 elems per weight slot

typedef _Float16 half8 __attribute__((ext_vector_type(8)));
typedef float float4v __attribute__((ext_vector_type(4)));

// workspace layout (bytes)
#define OFF_SF ((size_t)10 * WSLOT * 2)            // after 10 fp16 weight slots (40 MB)
#define OFF_SB (OFF_SF + (size_t)4 * SBUF * 4)     // after fp32 state [2 phase][2 layer]
#define OFF_BAR (OFF_SB + (size_t)4 * SBUF * 2)    // after fp16 state mirror

__device__ __forceinline__ half8 ld8(const _Float16* p) {
    return *reinterpret_cast<const half8*>(p);
}

__device__ __forceinline__ half8 cvt8(const float* p) {
    const float4v a = *reinterpret_cast<const float4v*>(p);
    const float4v b = *reinterpret_cast<const float4v*>(p + 4);
    half8 r;
    r[0] = (_Float16)a[0]; r[1] = (_Float16)a[1];
    r[2] = (_Float16)a[2]; r[3] = (_Float16)a[3];
    r[4] = (_Float16)b[0]; r[5] = (_Float16)b[1];
    r[6] = (_Float16)b[2]; r[7] = (_Float16)b[3];
    return r;
}

// sense-free barrier: monotone epoch counter, one atomic arrive per WG.
__device__ __forceinline__ void gbar(int* cnt, int* epoch, int target) {
    __syncthreads();
    if (threadIdx.x == 0) {
        __threadfence();  // publish my state writes (agent scope)
        int prev = __hip_atomic_fetch_add(cnt, 1, __ATOMIC_ACQ_REL, __HIP_MEMORY_SCOPE_AGENT);
        if (prev == NWG - 1) {
            __hip_atomic_store(cnt, 0, __ATOMIC_RELAXED, __HIP_MEMORY_SCOPE_AGENT);
            __hip_atomic_fetch_add(epoch, 1, __ATOMIC_RELEASE, __HIP_MEMORY_SCOPE_AGENT);
        } else {
            while (__hip_atomic_load(epoch, __ATOMIC_ACQUIRE, __HIP_MEMORY_SCOPE_AGENT) < target)
                __builtin_amdgcn_s_sleep(2);
        }
        __threadfence();  // invalidate caches so we see others' state writes
    }
    __syncthreads();
}

// ---- prep: transpose+convert weights to fp16 [n][k] ----
// slots: per layer l: slot l*5+0 = w_in[l]^T ; slots l*5+1..4 = w_h[l][d]^T
__global__ __launch_bounds__(256) void wprep(const float* __restrict__ w_in,
                                             const float* __restrict__ w_h,
                                             _Float16* __restrict__ Wt) {
    const int bid = (int)blockIdx.x;
    const int tk = bid & 31;           // k-tile (1024/32)
    const int tn = (bid >> 5) & 63;    // n-tile (2048/32)
    const int slot = bid >> 11;        // 0..9
    const int l = slot / 5;
    const int j = slot - l * 5;
    const float* __restrict__ src = (j == 0)
        ? (w_in + (size_t)l * WSLOT)
        : (w_h + (size_t)(l * ND + (j - 1)) * WSLOT);
    __shared__ float tile[32][33];
    const int tx = (int)(threadIdx.x & 31u);
    const int ty = (int)(threadIdx.x >> 5);  // 0..7
    const int n = tn * 32 + tx;
#pragma unroll
    for (int r = 0; r < 4; ++r) {
        const int k = tk * 32 + ty + r * 8;
        tile[ty + r * 8][tx] = src[(size_t)k * NH2 + n];  // coalesced read
    }
    __syncthreads();
    _Float16* __restrict__ dst = Wt + (size_t)slot * WSLOT;
#pragma unroll
    for (int r = 0; r < 4; ++r) {
        const int nn = tn * 32 + ty + r * 8;
        const int kk = tk * 32 + tx;
        dst[(size_t)nn * HID + kk] = (_Float16)tile[tx][ty + r * 8];  // coalesced write
    }
}

// ---- prep: copy initial state into phase 0, zero barrier ----
__global__ void sinit(const float* __restrict__ state, float* __restrict__ sf,
                      _Float16* __restrict__ sb, int* __restrict__ bar) {
    const int i = (int)(blockIdx.x * 256 + threadIdx.x);
    if (i < NL * SBUF) {
        const float v = state[i];  // [l][b][h] == phase0 [0][l][b][h]
        sf[i] = v;
        sb[i] = (_Float16)v;
    }
    if (i < 2) bar[i] = 0;
}

// ---- main sequential kernel ----
// 64 WGs x 256 threads. WG wg owns h-cols [wg*16, wg*16+16) and paired g-cols
// (+1024). Wave w owns batch tile [w*16, w*16+16). State double-buffered:
// phase layout [p][l][b][h].
__global__ __launch_bounds__(256) void rhn_main(
    const float* __restrict__ x, const float* __restrict__ bh,
    const _Float16* __restrict__ Wt, float* __restrict__ sf,
    _Float16* __restrict__ sb, float* __restrict__ out, int* __restrict__ bar) {
    const int lane = (int)(threadIdx.x & 63u);
    const int m0 = (int)(threadIdx.x >> 6) * 16;  // batch tile base
    const int n0 = (int)blockIdx.x * 16;          // h-col base
    const int lr = lane & 15;                     // m for A, n for B, col for C
    const int kofs = (lane >> 4) * 8;             // k quad offset
    int bcount = 0;
    int cur0 = 0, cur1 = 0;

    for (int t = 0; t < SEQ; ++t) {
        for (int l = 0; l < NL; ++l) {
            for (int d = 0; d < ND; ++d) {
                const int cl = (l == 0) ? cur0 : cur1;
                const int wrp = 1 - cl;
                const _Float16* __restrict__ srd =
                    sb + (size_t)(cl * NL + l) * SBUF + (size_t)(m0 + lr) * HID + kofs;
                const _Float16* __restrict__ Wh = Wt + (size_t)(l * 5 + 1 + d) * WSLOT;
                const _Float16* __restrict__ bhp = Wh + (size_t)(n0 + lr) * HID + kofs;
                const _Float16* __restrict__ bgp = Wh + (size_t)(HID + n0 + lr) * HID + kofs;
                float4v acch = {0.f, 0.f, 0.f, 0.f};
                float4v accg = {0.f, 0.f, 0.f, 0.f};
#pragma unroll 8
                for (int kb = 0; kb < HID; kb += 32) {
                    half8 a = ld8(srd + kb);
                    acch = __builtin_amdgcn_mfma_f32_16x16x32_f16(a, ld8(bhp + kb), acch, 0, 0, 0);
                    accg = __builtin_amdgcn_mfma_f32_16x16x32_f16(a, ld8(bgp + kb), accg, 0, 0, 0);
                }
                if (d == 0) {
                    // fuse input projection: + inp @ w_in[l]
                    const _Float16* __restrict__ Wi = Wt + (size_t)(l * 5) * WSLOT;
                    const _Float16* __restrict__ bih = Wi + (size_t)(n0 + lr) * HID + kofs;
                    const _Float16* __restrict__ big = Wi + (size_t)(HID + n0 + lr) * HID + kofs;
                    if (l == 0) {
                        const float* __restrict__ xr =
                            x + (size_t)t * SBUF + (size_t)(m0 + lr) * HID + kofs;
#pragma unroll 4
                        for (int kb = 0; kb < HID; kb += 32) {
                            half8 a = cvt8(xr + kb);
                            acch = __builtin_amdgcn_mfma_f32_16x16x32_f16(a, ld8(bih + kb), acch, 0, 0, 0);
                            accg = __builtin_amdgcn_mfma_f32_16x16x32_f16(a, ld8(big + kb), accg, 0, 0, 0);
                        }
                    } else {
                        // inp = layer0's fresh state (phase cur0)
                        const _Float16* __restrict__ s0r =
                            sb + (size_t)(cur0 * NL + 0) * SBUF + (size_t)(m0 + lr) * HID + kofs;
#pragma unroll 8
                        for (int kb = 0; kb < HID; kb += 32) {
                            half8 a = ld8(s0r + kb);
                            acch = __builtin_amdgcn_mfma_f32_16x16x32_f16(a, ld8(bih + kb), acch, 0, 0, 0);
                            accg = __builtin_amdgcn_mfma_f32_16x16x32_f16(a, ld8(big + kb), accg, 0, 0, 0);
                        }
                    }
                }
                // epilogue: C layout col=lane&15, row=(lane>>4)*4+i
                const float* __restrict__ bias = bh + (size_t)(l * ND + d) * NH2;
                const float bias_h = bias[n0 + lr];
                const float bias_g = bias[HID + n0 + lr];
                const float* __restrict__ sfr = sf + (size_t)(cl * NL + l) * SBUF;
                float* __restrict__ sfw = sf + (size_t)(wrp * NL + l) * SBUF;
                _Float16* __restrict__ sbw = sb + (size_t)(wrp * NL + l) * SBUF;
#pragma unroll
                for (int i = 0; i < 4; ++i) {
                    const int row = (lane >> 4) * 4 + i;
                    const int idx = (m0 + row) * HID + n0 + lr;
                    const float h = tanhf(acch[i] + bias_h);
                    const float g = 1.f / (1.f + expf(-(accg[i] + bias_g)));
                    const float so = sfr[idx];
                    const float sn = h * g + so * (1.f - g);
                    sfw[idx] = sn;
                    sbw[idx] = (_Float16)sn;
                    if (l == 1 && d == 3) out[(size_t)t * SBUF + idx] = sn;
                }
                if (l == 0) cur0 = wrp; else cur1 = wrp;
                gbar(bar, bar + 1, ++bcount);
            }
        }
    }
    // final states: each WG writes its own columns (self-written, no race)
    float* __restrict__ fout = out + (size_t)SEQ * SBUF;
    for (int e = (int)threadIdx.x; e < NL * NB * 16; e += 256) {
        const int l = e / (NB * 16);
        const int rem = e - l * (NB * 16);
        const int b = rem >> 4;
        const int c = rem & 15;
        const int idx = b * HID + n0 + c;
        const int p = (l == 0) ? cur0 : cur1;
        fout[(size_t)l * SBUF + idx] = sf[(size_t)(p * NL + l) * SBUF + idx];
    }
}

extern "C" void kernel_launch(void* const* d_in, const int* in_sizes, int n_in,
                              void* d_out, int out_size, void* d_ws, size_t ws_size,
                              hipStream_t stream) {
    (void)in_sizes; (void)n_in; (void)out_size; (void)ws_size;
    const float* x     = (const float*)d_in[0];
    const float* state = (const float*)d_in[1];
    const float* w_in  = (const float*)d_in[2];
    const float* w_h   = (const float*)d_in[3];
    const float* b_h   = (const float*)d_in[4];
    float* out = (float*)d_out;
    char* ws = (char*)d_ws;
    _Float16* Wt = (_Float16*)ws;
    float* sf    = (float*)(ws + OFF_SF);
    _Float16* sb = (_Float16*)(ws + OFF_SB);
    int* bar     = (int*)(ws + OFF_BAR);

    // 10 slots x 64 n-tiles x 32 k-tiles
    wprep<<<10 * 64 * 32, 256, 0, stream>>>(w_in, w_h, Wt);
    sinit<<<(NL * SBUF + 255) / 256, 256, 0, stream>>>(state, sf, sb, bar);
    rhn_main<<<NWG, 256, 0, stream>>>(x, b_h, Wt, sf, sb, out, bar);
}

// Round 2
// 103772.961 us; speedup vs baseline: 1.1068x; 1.1068x over previous
//
#include <hip/hip_runtime.h>
#include <math.h>
#include <stdint.h>

// RHN: SEQ=512, BATCH=64, HIDDEN=1024, 2 layers x 4 depth.
// Round 1: remove all agent-scope fences (they lowered to full L2
// writeback+invalidate per WG per phase = 524k L2 flushes). Cross-WG state
// traffic now uses per-access coherent (relaxed agent-scope atomic)
// loads/stores; weights stay cached in L1/L2/L3. Barrier = monotone counter
// with relaxed atomics only.

#define SEQ 512
#define NB 64
#define HID 1024
#define NH2 2048
#define NL 2
#define ND 4
#define NWG 64
#define SBUF (NB * HID)                       // 65536 elems per (phase,layer) state
#define WSLOT ((size_t)NH2 * (size_t)HID)     // 2097152 elems per weight slot

typedef _Float16 half8 __attribute__((ext_vector_type(8)));
typedef float float4v __attribute__((ext_vector_type(4)));

// workspace layout (bytes)
#define OFF_SF ((size_t)10 * WSLOT * 2)            // after 10 fp16 weight slots (40 MB)
#define OFF_SB (OFF_SF + (size_t)4 * SBUF * 4)     // after fp32 state [2 phase][2 layer]
#define OFF_BAR (OFF_SB + (size_t)4 * SBUF * 2)    // after fp16 state mirror

// plain cached 16B load (weights: read-only, cache-resident)
__device__ __forceinline__ half8 ld8(const _Float16* p) {
    return *reinterpret_cast<const half8*>(p);
}

// coherent 16B load as 2x8B relaxed agent-scope atomics (cross-WG state).
// Relaxed => no buffer_inv; compiler pipelines these like normal loads.
__device__ __forceinline__ half8 ldc8(const _Float16* p) {
    union { uint64_t u[2]; half8 h; } r;
    const uint64_t* q = reinterpret_cast<const uint64_t*>(p);
    r.u[0] = __hip_atomic_load(q, __ATOMIC_RELAXED, __HIP_MEMORY_SCOPE_AGENT);
    r.u[1] = __hip_atomic_load(q + 1, __ATOMIC_RELAXED, __HIP_MEMORY_SCOPE_AGENT);
    return r.h;
}

__device__ __forceinline__ half8 cvt8(const float* p) {
    const float4v a = *reinterpret_cast<const float4v*>(p);
    const float4v b = *reinterpret_cast<const float4v*>(p + 4);
    half8 r;
    r[0] = (_Float16)a[0]; r[1] = (_Float16)a[1];
    r[2] = (_Float16)a[2]; r[3] = (_Float16)a[3];
    r[4] = (_Float16)b[0]; r[5] = (_Float16)b[1];
    r[6] = (_Float16)b[2]; r[7] = (_Float16)b[3];
    return r;
}

// barrier: monotone arrival counter, relaxed atomics only (no cache flushes).
// __syncthreads() before arrive drains each wave's vmcnt (coherent stores are
// globally visible once vmcnt retires), providing release semantics.
__device__ __forceinline__ void gbar(int* cnt, int target) {
    __syncthreads();
    if (threadIdx.x == 0) {
        __hip_atomic_fetch_add(cnt, 1, __ATOMIC_RELAXED, __HIP_MEMORY_SCOPE_AGENT);
        while (__hip_atomic_load(cnt, __ATOMIC_RELAXED, __HIP_MEMORY_SCOPE_AGENT) <
               NWG * target)
            __builtin_amdgcn_s_sleep(4);
    }
    __syncthreads();
}

// ---- prep: transpose+convert weights to fp16 [n][k] ----
// slots: per layer l: slot l*5+0 = w_in[l]^T ; slots l*5+1..4 = w_h[l][d]^T
__global__ __launch_bounds__(256) void wprep(const float* __restrict__ w_in,
                                             const float* __restrict__ w_h,
                                             _Float16* __restrict__ Wt) {
    const int bid = (int)blockIdx.x;
    const int tk = bid & 31;           // k-tile (1024/32)
    const int tn = (bid >> 5) & 63;    // n-tile (2048/32)
    const int slot = bid >> 11;        // 0..9
    const int l = slot / 5;
    const int j = slot - l * 5;
    const float* __restrict__ src = (j == 0)
        ? (w_in + (size_t)l * WSLOT)
        : (w_h + (size_t)(l * ND + (j - 1)) * WSLOT);
    __shared__ float tile[32][33];
    const int tx = (int)(threadIdx.x & 31u);
    const int ty = (int)(threadIdx.x >> 5);  // 0..7
    const int n = tn * 32 + tx;
#pragma unroll
    for (int r = 0; r < 4; ++r) {
        const int k = tk * 32 + ty + r * 8;
        tile[ty + r * 8][tx] = src[(size_t)k * NH2 + n];  // coalesced read
    }
    __syncthreads();
    _Float16* __restrict__ dst = Wt + (size_t)slot * WSLOT;
#pragma unroll
    for (int r = 0; r < 4; ++r) {
        const int nn = tn * 32 + ty + r * 8;
        const int kk = tk * 32 + tx;
        dst[(size_t)nn * HID + kk] = (_Float16)tile[tx][ty + r * 8];  // coalesced write
    }
}

// ---- prep: copy initial state into phase 0, zero barrier ----
__global__ void sinit(const float* __restrict__ state, float* __restrict__ sf,
                      _Float16* __restrict__ sb, int* __restrict__ bar) {
    const int i = (int)(blockIdx.x * 256 + threadIdx.x);
    if (i < NL * SBUF) {
        const float v = state[i];  // [l][b][h] == phase0 [0][l][b][h]
        sf[i] = v;
        sb[i] = (_Float16)v;
    }
    if (i < 2) bar[i] = 0;
}

// ---- main sequential kernel ----
// 64 WGs x 256 threads. WG wg owns h-cols [wg*16, wg*16+16) and paired g-cols
// (+1024). Wave w owns batch tile [w*16, w*16+16). State double-buffered:
// phase layout [p][l][b][h].
__global__ __launch_bounds__(256) void rhn_main(
    const float* __restrict__ x, const float* __restrict__ bh,
    const _Float16* __restrict__ Wt, float* __restrict__ sf,
    _Float16* __restrict__ sb, float* __restrict__ out, int* __restrict__ bar) {
    const int lane = (int)(threadIdx.x & 63u);
    const int m0 = (int)(threadIdx.x >> 6) * 16;  // batch tile base
    const int n0 = (int)blockIdx.x * 16;          // h-col base
    const int lr = lane & 15;                     // m for A, n for B, col for C
    const int kofs = (lane >> 4) * 8;             // k quad offset
    int bcount = 0;
    int cur0 = 0, cur1 = 0;

    for (int t = 0; t < SEQ; ++t) {
        for (int l = 0; l < NL; ++l) {
            for (int d = 0; d < ND; ++d) {
                const int cl = (l == 0) ? cur0 : cur1;
                const int wrp = 1 - cl;
                const _Float16* __restrict__ srd =
                    sb + (size_t)(cl * NL + l) * SBUF + (size_t)(m0 + lr) * HID + kofs;
                const _Float16* __restrict__ Wh = Wt + (size_t)(l * 5 + 1 + d) * WSLOT;
                const _Float16* __restrict__ bhp = Wh + (size_t)(n0 + lr) * HID + kofs;
                const _Float16* __restrict__ bgp = Wh + (size_t)(HID + n0 + lr) * HID + kofs;
                float4v acch = {0.f, 0.f, 0.f, 0.f};
                float4v accg = {0.f, 0.f, 0.f, 0.f};
#pragma unroll 8
                for (int kb = 0; kb < HID; kb += 32) {
                    half8 a = ldc8(srd + kb);
                    acch = __builtin_amdgcn_mfma_f32_16x16x32_f16(a, ld8(bhp + kb), acch, 0, 0, 0);
                    accg = __builtin_amdgcn_mfma_f32_16x16x32_f16(a, ld8(bgp + kb), accg, 0, 0, 0);
                }
                if (d == 0) {
                    // fuse input projection: + inp @ w_in[l]
                    const _Float16* __restrict__ Wi = Wt + (size_t)(l * 5) * WSLOT;
                    const _Float16* __restrict__ bih = Wi + (size_t)(n0 + lr) * HID + kofs;
                    const _Float16* __restrict__ big = Wi + (size_t)(HID + n0 + lr) * HID + kofs;
                    if (l == 0) {
                        const float* __restrict__ xr =
                            x + (size_t)t * SBUF + (size_t)(m0 + lr) * HID + kofs;
#pragma unroll 4
                        for (int kb = 0; kb < HID; kb += 32) {
                            half8 a = cvt8(xr + kb);
                            acch = __builtin_amdgcn_mfma_f32_16x16x32_f16(a, ld8(bih + kb), acch, 0, 0, 0);
                            accg = __builtin_amdgcn_mfma_f32_16x16x32_f16(a, ld8(big + kb), accg, 0, 0, 0);
                        }
                    } else {
                        // inp = layer0's fresh state (phase cur0), cross-WG -> coherent
                        const _Float16* __restrict__ s0r =
                            sb + (size_t)(cur0 * NL + 0) * SBUF + (size_t)(m0 + lr) * HID + kofs;
#pragma unroll 8
                        for (int kb = 0; kb < HID; kb += 32) {
                            half8 a = ldc8(s0r + kb);
                            acch = __builtin_amdgcn_mfma_f32_16x16x32_f16(a, ld8(bih + kb), acch, 0, 0, 0);
                            accg = __builtin_amdgcn_mfma_f32_16x16x32_f16(a, ld8(big + kb), accg, 0, 0, 0);
                        }
                    }
                }
                // epilogue: C layout col=lane&15, row=(lane>>4)*4+i
                const float* __restrict__ bias = bh + (size_t)(l * ND + d) * NH2;
                const float bias_h = bias[n0 + lr];
                const float bias_g = bias[HID + n0 + lr];
                const float* __restrict__ sfr = sf + (size_t)(cl * NL + l) * SBUF;
                float* __restrict__ sfw = sf + (size_t)(wrp * NL + l) * SBUF;
                _Float16* __restrict__ sbw = sb + (size_t)(wrp * NL + l) * SBUF;
#pragma unroll
                for (int i = 0; i < 4; ++i) {
                    const int row = (lane >> 4) * 4 + i;
                    const int idx = (m0 + row) * HID + n0 + lr;
                    const float h = tanhf(acch[i] + bias_h);
                    const float g = 1.f / (1.f + expf(-(accg[i] + bias_g)));
                    const float so = sfr[idx];               // own wave wrote it: cached
                    const float sn = h * g + so * (1.f - g);
                    sfw[idx] = sn;                            // own-use only: cached
                    // coherent fp16 mirror store: pack adjacent cols, 4B dwords
                    const unsigned short mine =
                        (unsigned short)__builtin_bit_cast(unsigned short, (_Float16)sn);
                    const unsigned short oth =
                        (unsigned short)__shfl_xor((int)mine, 1, 64);
                    if ((lr & 1) == 0) {
                        const uint32_t pk = (uint32_t)mine | ((uint32_t)oth << 16);
                        uint32_t* dst = reinterpret_cast<uint32_t*>(sbw + idx);
                        __hip_atomic_store(dst, pk, __ATOMIC_RELAXED,
                                           __HIP_MEMORY_SCOPE_AGENT);
                    }
                    if (l == 1 && d == 3) out[(size_t)t * SBUF + idx] = sn;
                }
                if (l == 0) cur0 = wrp; else cur1 = wrp;
                gbar(bar, ++bcount);
            }
        }
    }
    // final states: each WG writes its own columns (self-written, no race)
    float* __restrict__ fout = out + (size_t)SEQ * SBUF;
    for (int e = (int)threadIdx.x; e < NL * NB * 16; e += 256) {
        const int l = e / (NB * 16);
        const int rem = e - l * (NB * 16);
        const int b = rem >> 4;
        const int c = rem & 15;
        const int idx = b * HID + n0 + c;
        const int p = (l == 0) ? cur0 : cur1;
        fout[(size_t)l * SBUF + idx] = sf[(size_t)(p * NL + l) * SBUF + idx];
    }
}

extern "C" void kernel_launch(void* const* d_in, const int* in_sizes, int n_in,
                              void* d_out, int out_size, void* d_ws, size_t ws_size,
                              hipStream_t stream) {
    (void)in_sizes; (void)n_in; (void)out_size; (void)ws_size;
    const float* x     = (const float*)d_in[0];
    const float* state = (const float*)d_in[1];
    const float* w_in  = (const float*)d_in[2];
    const float* w_h   = (const float*)d_in[3];
    const float* b_h   = (const float*)d_in[4];
    float* out = (float*)d_out;
    char* ws = (char*)d_ws;
    _Float16* Wt = (_Float16*)ws;
    float* sf    = (float*)(ws + OFF_SF);
    _Float16* sb = (_Float16*)(ws + OFF_SB);
    int* bar     = (int*)(ws + OFF_BAR);

    // 10 slots x 64 n-tiles x 32 k-tiles
    wprep<<<10 * 64 * 32, 256, 0, stream>>>(w_in, w_h, Wt);
    sinit<<<(NL * SBUF + 255) / 256, 256, 0, stream>>>(state, sf, sb, bar);
    rhn_main<<<NWG, 256, 0, stream>>>(x, b_h, Wt, sf, sb, out, bar);
}

// Round 3
// 64507.086 us; speedup vs baseline: 1.7805x; 1.6087x over previous
//
#include <hip/hip_runtime.h>
#include <math.h>
#include <stdint.h>

// RHN round 2: LDS-resident weights (depth-specialized WGs), input projections
// hoisted into bulk GEMMs, two sequential scans (layer 0 then layer 1).
// Phase = one depth micro-step; 64 active WGs/phase; barrier = monotone
// counter, relaxed agent atomics only.

#define SEQ 512
#define NB 64
#define HID 1024
#define NH2 2048
#define NL 2
#define ND 4
#define SBUF (NB * HID)                    // 65536
#define WSLOT ((size_t)NH2 * (size_t)HID)  // 2097152 elems per slot
#define MROWS (SEQ * NB)                   // 32768

typedef _Float16 half8 __attribute__((ext_vector_type(8)));
typedef float float4v __attribute__((ext_vector_type(4)));

// ---- workspace layout (bytes) ----
#define OFF_HG0 ((size_t)10 * WSLOT * 2)                 // 41943040  (Wt 40MB)
#define OFF_SSEQ (OFF_HG0 + (size_t)MROWS * NH2 * 2)     // +134217728
#define OFF_MIR (OFF_SSEQ + (size_t)MROWS * HID * 2)     // +67108864
#define OFF_CAR (OFF_MIR + (size_t)4 * SBUF * 2)         // 4 mirrors fp16
#define OFF_CNT (OFF_CAR + (size_t)2 * SBUF * 4)         // 2 carries fp32

__device__ __forceinline__ half8 ld8(const _Float16* p) {
    return *reinterpret_cast<const half8*>(p);
}

// coherent 16B load = 2x8B relaxed agent atomics (bypasses non-coherent L1/L2)
__device__ __forceinline__ half8 ldc8(const _Float16* p) {
    union { uint64_t u[2]; half8 h; } r;
    const uint64_t* q = reinterpret_cast<const uint64_t*>(p);
    r.u[0] = __hip_atomic_load(q, __ATOMIC_RELAXED, __HIP_MEMORY_SCOPE_AGENT);
    r.u[1] = __hip_atomic_load(q + 1, __ATOMIC_RELAXED, __HIP_MEMORY_SCOPE_AGENT);
    return r.h;
}

__device__ __forceinline__ half8 cvt8(const float* p) {
    const float4v a = *reinterpret_cast<const float4v*>(p);
    const float4v b = *reinterpret_cast<const float4v*>(p + 4);
    half8 r;
    r[0] = (_Float16)a[0]; r[1] = (_Float16)a[1];
    r[2] = (_Float16)a[2]; r[3] = (_Float16)a[3];
    r[4] = (_Float16)b[0]; r[5] = (_Float16)b[1];
    r[6] = (_Float16)b[2]; r[7] = (_Float16)b[3];
    return r;
}

// ---- prep: transpose+convert weights to fp16 [n][k] ----
// slots per layer l: l*5+0 = w_in[l]^T ; l*5+1..4 = w_h[l][d]^T
__global__ __launch_bounds__(256) void wprep(const float* __restrict__ w_in,
                                             const float* __restrict__ w_h,
                                             _Float16* __restrict__ Wt) {
    const int bid = (int)blockIdx.x;
    const int tk = bid & 31;
    const int tn = (bid >> 5) & 63;
    const int slot = bid >> 11;  // 0..9
    const int l = slot / 5;
    const int j = slot - l * 5;
    const float* __restrict__ src = (j == 0)
        ? (w_in + (size_t)l * WSLOT)
        : (w_h + (size_t)(l * ND + (j - 1)) * WSLOT);
    __shared__ float tile[32][33];
    const int tx = (int)(threadIdx.x & 31u);
    const int ty = (int)(threadIdx.x >> 5);
    const int n = tn * 32 + tx;
#pragma unroll
    for (int r = 0; r < 4; ++r) {
        const int k = tk * 32 + ty + r * 8;
        tile[ty + r * 8][tx] = src[(size_t)k * NH2 + n];
    }
    __syncthreads();
    _Float16* __restrict__ dst = Wt + (size_t)slot * WSLOT;
#pragma unroll
    for (int r = 0; r < 4; ++r) {
        const int nn = tn * 32 + ty + r * 8;
        const int kk = tk * 32 + tx;
        dst[(size_t)nn * HID + kk] = (_Float16)tile[tx][ty + r * 8];
    }
}

// ---- prep: init mirrors (fp16) + carries (fp32) + counters ----
__global__ void sinit2(const float* __restrict__ state, _Float16* __restrict__ mir0,
                       float* __restrict__ car0, _Float16* __restrict__ mir1,
                       float* __restrict__ car1, int* __restrict__ cnts) {
    const int i = (int)(blockIdx.x * 256 + threadIdx.x);
    if (i < SBUF) {
        const float v0 = state[i];
        const float v1 = state[SBUF + i];
        mir0[i] = (_Float16)v0; car0[i] = v0;
        mir1[i] = (_Float16)v1; car1[i] = v1;
    }
    if (i < 8) cnts[i] = 0;
}

// ---- bulk input-projection GEMM: C[m][n] = A[m][:] @ Bslot[n][:], fp16 out ----
template <bool AF16>
__global__ __launch_bounds__(256) void gemm_proj(const void* __restrict__ Av,
                                                 const _Float16* __restrict__ Bslot,
                                                 _Float16* __restrict__ C) {
    const int bid = (int)blockIdx.x;
    const int nt = bid & 31;    // 32 n-tiles of 64
    const int mt = bid >> 5;    // 512 m-tiles of 64
    const int lane = (int)(threadIdx.x & 63u);
    const int wv = (int)(threadIdx.x >> 6);
    const int lr = lane & 15;
    const int kofs = (lane >> 4) * 8;
    const int m = mt * 64 + wv * 16 + lr;
    float4v acc[4];
#pragma unroll
    for (int i = 0; i < 4; ++i) acc[i] = (float4v){0.f, 0.f, 0.f, 0.f};
#pragma unroll 4
    for (int kb = 0; kb < 32; ++kb) {
        half8 a;
        if (AF16) a = ld8((const _Float16*)Av + (size_t)m * HID + kb * 32 + kofs);
        else      a = cvt8((const float*)Av + (size_t)m * HID + kb * 32 + kofs);
#pragma unroll
        for (int ct = 0; ct < 4; ++ct) {
            const int n = nt * 64 + ct * 16 + lr;
            half8 b = ld8(Bslot + (size_t)n * HID + kb * 32 + kofs);
            acc[ct] = __builtin_amdgcn_mfma_f32_16x16x32_f16(a, b, acc[ct], 0, 0, 0);
        }
    }
#pragma unroll
    for (int ct = 0; ct < 4; ++ct) {
#pragma unroll
        for (int i = 0; i < 4; ++i) {
            const int row = mt * 64 + wv * 16 + (lane >> 4) * 4 + i;
            const int col = nt * 64 + ct * 16 + lr;
            const unsigned short mine =
                __builtin_bit_cast(unsigned short, (_Float16)acc[ct][i]);
            const unsigned short oth = (unsigned short)__shfl_xor((int)mine, 1, 64);
            if ((lane & 1) == 0) {
                const uint32_t pk = (uint32_t)mine | ((uint32_t)oth << 16);
                *reinterpret_cast<uint32_t*>(C + (size_t)row * NH2 + col) = pk;
            }
        }
    }
}

// ---- sequential scan over one layer: 512 t x 4 d phases ----
// 256 WGs: d = wg>>6 (depth specialization), cg = wg&63 (16 h-cols + 16 g-cols).
// Weights fragment-packed in 64KB dynamic LDS. 64 active WGs per phase.
__global__ __launch_bounds__(256) void rhn_scan(
    const _Float16* __restrict__ Wt, int slotBase,
    const float* __restrict__ bias,     // b_h[l] : [ND][NH2]
    const _Float16* __restrict__ hg0,   // [MROWS][NH2] fp16 precomputed proj
    _Float16* __restrict__ mirA, _Float16* __restrict__ mirB,  // state fp16 dbuf
    float* __restrict__ carry,          // [NB][HID] fp32 coherent carry
    int* __restrict__ cnt,
    _Float16* __restrict__ sseq,        // layer0: [MROWS][HID] fp16 (else null)
    float* __restrict__ outp,           // layer1: [SEQ][NB][HID] fp32 (else null)
    float* __restrict__ fout) {         // final state [NB][HID] fp32
    extern __shared__ _Float16 lds[];   // [2 tiles][32 kb][64 lanes][8] = 64 KB
    const int wg = (int)blockIdx.x;
    const int d = wg >> 6;
    const int cg = wg & 63;
    const int tid = (int)threadIdx.x;
    const int lane = tid & 63;
    const int m0 = (tid >> 6) * 16;
    const int lr = lane & 15;
    const int kofs = (lane >> 4) * 8;
    const _Float16* __restrict__ slot = Wt + (size_t)(slotBase + d) * WSLOT;

    // fill LDS with packed B-fragments (once per scan)
    for (int i = 0; i < 16; ++i) {
        const int flat = i * 256 + tid;        // [tile][kb][lane]
        const int tile = flat >> 11;
        const int kb = (flat >> 6) & 31;
        const int ln = flat & 63;
        const int col = tile * HID + cg * 16 + (ln & 15);
        *reinterpret_cast<half8*>(lds + (size_t)flat * 8) =
            ld8(slot + (size_t)col * HID + kb * 32 + (ln >> 4) * 8);
    }
    __syncthreads();

    const int colh = cg * 16 + lr;
    const float bh = bias[d * NH2 + colh];
    const float bg = bias[d * NH2 + HID + colh];

    for (int t = 0; t < SEQ; ++t) {
        const int gp = t * 4 + d;
        // wait for all prior phases (64 WG-arrivals each)
        if (lane == 0) {
            while (__hip_atomic_load(cnt, __ATOMIC_RELAXED, __HIP_MEMORY_SCOPE_AGENT) <
                   64 * gp)
                __builtin_amdgcn_s_sleep(8);
        }
        __asm__ __volatile__("" ::: "memory");  // no load motion across the poll

        const _Float16* __restrict__ mr = (gp & 1) ? mirB : mirA;
        const _Float16* __restrict__ arow = mr + (size_t)(m0 + lr) * HID + kofs;
        float4v acch = {0.f, 0.f, 0.f, 0.f};
        float4v accg = {0.f, 0.f, 0.f, 0.f};
#pragma unroll 8
        for (int kb = 0; kb < 32; ++kb) {
            half8 a = ldc8(arow + kb * 32);
            half8 bhf = *reinterpret_cast<const half8*>(lds + (size_t)(kb * 64 + lane) * 8);
            half8 bgf =
                *reinterpret_cast<const half8*>(lds + (size_t)((32 + kb) * 64 + lane) * 8);
            acch = __builtin_amdgcn_mfma_f32_16x16x32_f16(a, bhf, acch, 0, 0, 0);
            accg = __builtin_amdgcn_mfma_f32_16x16x32_f16(a, bgf, accg, 0, 0, 0);
        }

        _Float16* __restrict__ mw = ((gp + 1) & 1) ? mirB : mirA;
#pragma unroll
        for (int i = 0; i < 4; ++i) {
            const int gr = m0 + (lane >> 4) * 4 + i;
            const size_t idx = (size_t)gr * HID + colh;
            float ah = acch[i] + bh;
            float ag = accg[i] + bg;
            if (d == 0) {
                const size_t hb = (size_t)(t * NB + gr) * NH2 + colh;
                ah += (float)hg0[hb];
                ag += (float)hg0[hb + HID];
            }
            const float sold =
                __hip_atomic_load(carry + idx, __ATOMIC_RELAXED, __HIP_MEMORY_SCOPE_AGENT);
            const float hv = tanhf(ah);
            const float gv = 1.f / (1.f + expf(-ag));
            const float sn = hv * gv + sold * (1.f - gv);
            __hip_atomic_store(carry + idx, sn, __ATOMIC_RELAXED,
                               __HIP_MEMORY_SCOPE_AGENT);
            const unsigned short mine = __builtin_bit_cast(unsigned short, (_Float16)sn);
            const unsigned short oth = (unsigned short)__shfl_xor((int)mine, 1, 64);
            const uint32_t pk = (uint32_t)mine | ((uint32_t)oth << 16);
            if ((lane & 1) == 0) {
                __hip_atomic_store(reinterpret_cast<uint32_t*>(mw + idx), pk,
                                   __ATOMIC_RELAXED, __HIP_MEMORY_SCOPE_AGENT);
            }
            if (d == 3) {
                if (sseq) {
                    if ((lane & 1) == 0)
                        *reinterpret_cast<uint32_t*>(sseq + (size_t)t * SBUF + idx) = pk;
                } else {
                    outp[(size_t)t * SBUF + idx] = sn;
                }
                if (t == SEQ - 1) fout[idx] = sn;
            }
        }
        __syncthreads();  // drains all 4 waves' stores (vmcnt 0) before arrive
        if (tid == 0)
            __hip_atomic_fetch_add(cnt, 1, __ATOMIC_RELAXED, __HIP_MEMORY_SCOPE_AGENT);
    }
}

extern "C" void kernel_launch(void* const* d_in, const int* in_sizes, int n_in,
                              void* d_out, int out_size, void* d_ws, size_t ws_size,
                              hipStream_t stream) {
    (void)in_sizes; (void)n_in; (void)out_size; (void)ws_size;
    const float* x     = (const float*)d_in[0];
    const float* state = (const float*)d_in[1];
    const float* w_in  = (const float*)d_in[2];
    const float* w_h   = (const float*)d_in[3];
    const float* b_h   = (const float*)d_in[4];
    float* out = (float*)d_out;
    char* ws = (char*)d_ws;
    _Float16* Wt   = (_Float16*)ws;
    _Float16* HG0  = (_Float16*)(ws + OFF_HG0);
    _Float16* Sseq = (_Float16*)(ws + OFF_SSEQ);
    _Float16* mir0a = (_Float16*)(ws + OFF_MIR);
    _Float16* mir0b = mir0a + SBUF;
    _Float16* mir1a = mir0b + SBUF;
    _Float16* mir1b = mir1a + SBUF;
    float* car0 = (float*)(ws + OFF_CAR);
    float* car1 = car0 + SBUF;
    int* cnts = (int*)(ws + OFF_CNT);

    (void)hipFuncSetAttribute((const void*)rhn_scan,
                              hipFuncAttributeMaxDynamicSharedMemorySize, 65536);

    wprep<<<10 * 64 * 32, 256, 0, stream>>>(w_in, w_h, Wt);
    sinit2<<<(SBUF + 255) / 256, 256, 0, stream>>>(state, mir0a, car0, mir1a, car1, cnts);
    // HG0_l0 = x @ w_in[0]
    gemm_proj<false><<<512 * 32, 256, 0, stream>>>((const void*)x, Wt + 0 * WSLOT, HG0);
    // scan layer 0 (writes Sseq fp16, fout[0])
    rhn_scan<<<256, 256, 65536, stream>>>(Wt, 1, b_h, HG0, mir0a, mir0b, car0, cnts,
                                          Sseq, (float*)nullptr,
                                          out + (size_t)SEQ * SBUF);
    // HG0_l1 = Sseq @ w_in[1]  (reuse HG0 buffer)
    gemm_proj<true><<<512 * 32, 256, 0, stream>>>((const void*)Sseq, Wt + 5 * WSLOT, HG0);
    // scan layer 1 (writes out[t], fout[1])
    rhn_scan<<<256, 256, 65536, stream>>>(Wt, 6, b_h + (size_t)ND * NH2, HG0, mir1a,
                                          mir1b, car1, cnts + 1, (_Float16*)nullptr,
                                          out, out + (size_t)SEQ * SBUF + SBUF);
}